// Round 1
// baseline (774.537 us; speedup 1.0000x reference)
//
#include <hip/hip_runtime.h>
#include <hip/hip_bf16.h>
#include <stdint.h>

// GCN 2-layer forward: out = A_hat @ relu(A_hat @ (X W1^T + b1)) W2^T + b2
// A_hat = D^-1/2 (A + I) D^-1/2, pull-based CSR aggregation (no fp32 atomics).

#define TPB 256

// ---------------------------------------------------------------------------
// dtype probe: edge_index may arrive as int32 or int64. If int64 (values < 2^31,
// non-negative), every odd 32-bit word of the first 64 entries is 0.
__global__ void detect64_kernel(const int* __restrict__ ei32, int* __restrict__ flag) {
    if (threadIdx.x == 0 && blockIdx.x == 0) {
        int is64 = 1;
        for (int t = 0; t < 64; ++t) {
            if (ei32[2 * t + 1] != 0) { is64 = 0; break; }
        }
        *flag = is64;
    }
}

__device__ __forceinline__ int load_edge(const void* ei, int is64, int pos) {
    return is64 ? (int)((const long long*)ei)[pos] : ((const int*)ei)[pos];
}

// ---------------------------------------------------------------------------
__global__ __launch_bounds__(TPB) void count_deg_kernel(const void* __restrict__ ei, int E,
                                                        int* __restrict__ cnt,
                                                        const int* __restrict__ flag, int N) {
    int e = blockIdx.x * TPB + threadIdx.x;
    if (e >= E) return;
    int is64 = *flag;
    int r = load_edge(ei, is64, e);
    if ((unsigned)r < (unsigned)N) atomicAdd(&cnt[r], 1);
}

// ---------------------------------------------------------------------------
// scan part 1: per-1024-element tile local exclusive scan + tile totals; also dis[i]
__global__ __launch_bounds__(TPB) void scan1_kernel(const int* __restrict__ cnt,
                                                    int* __restrict__ offs,
                                                    int* __restrict__ bsums,
                                                    float* __restrict__ dis, int N) {
    __shared__ int sm[TPB];
    int tid = threadIdx.x;
    int base = blockIdx.x * 1024 + tid * 4;
    int4 v = make_int4(0, 0, 0, 0);
    if (base + 3 < N) {
        v = *(const int4*)(cnt + base);
    } else {
        if (base + 0 < N) v.x = cnt[base + 0];
        if (base + 1 < N) v.y = cnt[base + 1];
        if (base + 2 < N) v.z = cnt[base + 2];
        if (base + 3 < N) v.w = cnt[base + 3];
    }
    int tsum = v.x + v.y + v.z + v.w;
    sm[tid] = tsum;
    __syncthreads();
    for (int o = 1; o < TPB; o <<= 1) {
        int x = (tid >= o) ? sm[tid - o] : 0;
        __syncthreads();
        sm[tid] += x;
        __syncthreads();
    }
    int excl = sm[tid] - tsum;
    int4 o4;
    o4.x = excl;
    o4.y = o4.x + v.x;
    o4.z = o4.y + v.y;
    o4.w = o4.z + v.z;
    if (base + 3 < N) {
        *(int4*)(offs + base) = o4;
    } else {
        if (base + 0 < N) offs[base + 0] = o4.x;
        if (base + 1 < N) offs[base + 1] = o4.y;
        if (base + 2 < N) offs[base + 2] = o4.z;
        if (base + 3 < N) offs[base + 3] = o4.w;
    }
    if (tid == TPB - 1) bsums[blockIdx.x] = sm[TPB - 1];
    // dis = (deg+self)^{-1/2}
    int vv[4] = {v.x, v.y, v.z, v.w};
#pragma unroll
    for (int t = 0; t < 4; ++t) {
        int i = base + t;
        if (i < N) dis[i] = rsqrtf((float)vv[t] + 1.0f);
    }
}

// scan part 2: exclusive scan over tile sums (nb <= 128)
__global__ void scan2_kernel(int* __restrict__ bsums, int nb) {
    __shared__ int sm[128];
    int tid = threadIdx.x;
    int v = (tid < nb) ? bsums[tid] : 0;
    sm[tid] = v;
    __syncthreads();
    for (int o = 1; o < 128; o <<= 1) {
        int x = (tid >= o) ? sm[tid - o] : 0;
        __syncthreads();
        sm[tid] += x;
        __syncthreads();
    }
    if (tid < nb) bsums[tid] = sm[tid] - v;  // exclusive
}

// scan part 3: add tile offsets
__global__ __launch_bounds__(TPB) void scan3_kernel(int* __restrict__ offs,
                                                    const int* __restrict__ bsums, int N) {
    int add = bsums[blockIdx.x];
    int base = blockIdx.x * 1024 + threadIdx.x * 4;
    if (base + 3 < N) {
        int4 v = *(int4*)(offs + base);
        v.x += add; v.y += add; v.z += add; v.w += add;
        *(int4*)(offs + base) = v;
    } else {
#pragma unroll
        for (int t = 0; t < 4; ++t)
            if (base + t < N) offs[base + t] += add;
    }
}

// ---------------------------------------------------------------------------
__global__ __launch_bounds__(TPB) void fill_csr_kernel(const void* __restrict__ ei, int E,
                                                       const int* __restrict__ offs,
                                                       int* __restrict__ cursor,
                                                       int* __restrict__ csr,
                                                       const int* __restrict__ flag, int N) {
    int e = blockIdx.x * TPB + threadIdx.x;
    if (e >= E) return;
    int is64 = *flag;
    int r = load_edge(ei, is64, e);
    int c = load_edge(ei, is64, E + e);
    if ((unsigned)r < (unsigned)N && (unsigned)c < (unsigned)N) {
        int pos = offs[r] + atomicAdd(&cursor[r], 1);
        csr[pos] = c;
    }
}

// ---------------------------------------------------------------------------
// fp32 GEMM: H[n, j0:j0+OTILE] = X[n,:] @ W[j0:j0+OTILE,:]^T + b.  K fixed = 128.
// W tile transposed into LDS (padded stride); X streamed from global into registers.
template <int OTILE, int NPT, int OUTF>
__global__ __launch_bounds__(TPB) void gemm_kernel(const float* __restrict__ X,
                                                   const float* __restrict__ W,
                                                   const float* __restrict__ bias,
                                                   float* __restrict__ H, int N) {
    constexpr int K = 128;
    constexpr int QUADS = OTILE / 4;        // 16
    constexpr int GROUPS = TPB / QUADS;     // 16
    constexpr int NPB = GROUPS * NPT;       // nodes per block
    constexpr int WST = OTILE + 4;          // padded LDS row stride (floats)
    __shared__ float Wt[K * WST];

    const int tid = threadIdx.x;
    const int j0 = blockIdx.y * OTILE;
    const float* Wsub = W + j0 * K;
    for (int idx = tid; idx < OTILE * K; idx += TPB) {
        int j = idx >> 7;      // row within tile
        int k = idx & 127;
        Wt[k * WST + j] = Wsub[idx];
    }
    __syncthreads();

    const int j4 = tid % QUADS;
    const int g = tid / QUADS;
    const int node0 = blockIdx.x * NPB + g * NPT;
    const float4* Xv = (const float4*)X;

    bool valid[NPT];
#pragma unroll
    for (int np = 0; np < NPT; ++np) valid[np] = (node0 + np) < N;

    float acc[NPT][4];
#pragma unroll
    for (int a = 0; a < NPT; ++a)
#pragma unroll
        for (int b = 0; b < 4; ++b) acc[a][b] = 0.0f;

#pragma unroll 2
    for (int k4 = 0; k4 < K / 4; ++k4) {
        float4 w0 = *(const float4*)&Wt[(4 * k4 + 0) * WST + 4 * j4];
        float4 w1 = *(const float4*)&Wt[(4 * k4 + 1) * WST + 4 * j4];
        float4 w2 = *(const float4*)&Wt[(4 * k4 + 2) * WST + 4 * j4];
        float4 w3 = *(const float4*)&Wt[(4 * k4 + 3) * WST + 4 * j4];
#pragma unroll
        for (int np = 0; np < NPT; ++np) {
            float4 xv = valid[np] ? Xv[(node0 + np) * (K / 4) + k4]
                                  : make_float4(0.f, 0.f, 0.f, 0.f);
            acc[np][0] += xv.x * w0.x + xv.y * w1.x + xv.z * w2.x + xv.w * w3.x;
            acc[np][1] += xv.x * w0.y + xv.y * w1.y + xv.z * w2.y + xv.w * w3.y;
            acc[np][2] += xv.x * w0.z + xv.y * w1.z + xv.z * w2.z + xv.w * w3.z;
            acc[np][3] += xv.x * w0.w + xv.y * w1.w + xv.z * w2.w + xv.w * w3.w;
        }
    }

    const float4 bv = *(const float4*)&bias[j0 + 4 * j4];
#pragma unroll
    for (int np = 0; np < NPT; ++np) {
        int node = node0 + np;
        if (node < N) {
            float4 r = make_float4(acc[np][0] + bv.x, acc[np][1] + bv.y,
                                   acc[np][2] + bv.z, acc[np][3] + bv.w);
            ((float4*)H)[node * (OUTF / 4) + (j0 >> 2) + j4] = r;
        }
    }
}

// ---------------------------------------------------------------------------
// Pull aggregation: one wave per node. out[i] = dis[i]^2*H[i] + sum_e dis[i]*dis[c]*H[c]
template <int F, bool RELU>
__global__ __launch_bounds__(TPB) void agg_kernel(const float* __restrict__ H,
                                                  const int* __restrict__ csr,
                                                  const int* __restrict__ offs,
                                                  const int* __restrict__ cnt,
                                                  const float* __restrict__ dis,
                                                  float* __restrict__ out, int N) {
    int w = (blockIdx.x * TPB + threadIdx.x) >> 6;
    if (w >= N) return;
    int lane = threadIdx.x & 63;
    float di = dis[w];
    int s = offs[w];
    int d = cnt[w];
    if (F == 128) {
        const float2* Hp = (const float2*)H;
        float2 acc = Hp[w * 64 + lane];
        acc.x *= di * di;
        acc.y *= di * di;
        for (int e = 0; e < d; ++e) {
            int c = csr[s + e];
            if ((unsigned)c >= (unsigned)N) continue;  // safety (never for valid input)
            float wt = di * dis[c];
            float2 h = Hp[c * 64 + lane];
            acc.x += wt * h.x;
            acc.y += wt * h.y;
        }
        if (RELU) { acc.x = fmaxf(acc.x, 0.f); acc.y = fmaxf(acc.y, 0.f); }
        ((float2*)out)[w * 64 + lane] = acc;
    } else {  // F == 64
        float acc = di * di * H[w * 64 + lane];
        for (int e = 0; e < d; ++e) {
            int c = csr[s + e];
            if ((unsigned)c >= (unsigned)N) continue;
            acc += di * dis[c] * H[c * 64 + lane];
        }
        if (RELU) acc = fmaxf(acc, 0.f);
        out[w * 64 + lane] = acc;
    }
}

// ---------------------------------------------------------------------------
extern "C" void kernel_launch(void* const* d_in, const int* in_sizes, int n_in,
                              void* d_out, int out_size, void* d_ws, size_t ws_size,
                              hipStream_t stream) {
    const float* x  = (const float*)d_in[0];
    const void*  ei = d_in[1];
    const float* W1 = (const float*)d_in[3];
    const float* b1 = (const float*)d_in[4];
    const float* W2 = (const float*)d_in[5];
    const float* b2 = (const float*)d_in[6];
    float* out = (float*)d_out;

    const int IN = 128, HID = 128, OUT = 64;
    const int N = in_sizes[0] / IN;
    const int E = in_sizes[1] / 2;

    char* ws = (char*)d_ws;
    size_t off = 0;
    auto alloc = [&](size_t bytes) -> void* {
        void* p = (void*)(ws + off);
        off += (bytes + 255) & ~(size_t)255;
        return p;
    };
    int*   cnt    = (int*)alloc((size_t)N * 4);
    int*   cursor = (int*)alloc((size_t)N * 4);
    int*   offs   = (int*)alloc((size_t)N * 4);
    int*   bsums  = (int*)alloc(512);
    int*   flag   = (int*)alloc(256);
    float* dis    = (float*)alloc((size_t)N * 4);
    int*   csr    = (int*)alloc((size_t)E * 4);
    float* H1     = (float*)alloc((size_t)N * HID * 4);
    float* R1     = (float*)alloc((size_t)N * HID * 4);
    float* H2     = H1;  // reuse: H1 dead after agg1

    hipMemsetAsync(cnt, 0, (size_t)N * 4, stream);
    hipMemsetAsync(cursor, 0, (size_t)N * 4, stream);

    detect64_kernel<<<1, 64, 0, stream>>>((const int*)ei, flag);

    int egrid = (E + TPB - 1) / TPB;
    count_deg_kernel<<<egrid, TPB, 0, stream>>>(ei, E, cnt, flag, N);

    int nb = (N + 1023) / 1024;
    scan1_kernel<<<nb, TPB, 0, stream>>>(cnt, offs, bsums, dis, N);
    scan2_kernel<<<1, 128, 0, stream>>>(bsums, nb);
    scan3_kernel<<<nb, TPB, 0, stream>>>(offs, bsums, N);

    fill_csr_kernel<<<egrid, TPB, 0, stream>>>(ei, E, offs, cursor, csr, flag, N);

    // layer 1: H1 = X@W1^T + b1 ; R1 = relu(A_hat @ H1)
    {
        dim3 grid((N + 63) / 64, HID / 64);
        gemm_kernel<64, 4, 128><<<grid, TPB, 0, stream>>>(x, W1, b1, H1, N);
    }
    agg_kernel<128, true><<<(N + 3) / 4, TPB, 0, stream>>>(H1, csr, offs, cnt, dis, R1, N);

    // layer 2: H2 = R1@W2^T + b2 ; out = A_hat @ H2
    {
        dim3 grid((N + 63) / 64, OUT / 64);
        gemm_kernel<64, 4, 64><<<grid, TPB, 0, stream>>>(R1, W2, b2, H2, N);
    }
    agg_kernel<64, false><<<(N + 3) / 4, TPB, 0, stream>>>(H2, csr, offs, cnt, dis, out, N);
}

// Round 2
// 612.619 us; speedup vs baseline: 1.2643x; 1.2643x over previous
//
#include <hip/hip_runtime.h>
#include <hip/hip_bf16.h>
#include <stdint.h>

// GCN 2-layer forward: out = A_hat @ relu(A_hat @ (X W1^T + b1)) W2^T + b2
// A_hat = D^-1/2 (A + I) D^-1/2, pull-based CSR aggregation (no fp32 atomics).
// R1 trick: GEMM epilogue pre-scales rows by dis[n], so aggregation is
// out[i] = dis[i] * (H'[i] + sum_e H'[col]) — edge loop is gather+add only.

#define TPB 256

// ---------------------------------------------------------------------------
// dtype probe: edge_index may arrive as int32 or int64. If int64 (values < 2^31,
// non-negative), every odd 32-bit word of the first 64 entries is 0.
__global__ void detect64_kernel(const int* __restrict__ ei32, int* __restrict__ flag) {
    if (threadIdx.x == 0 && blockIdx.x == 0) {
        int is64 = 1;
        for (int t = 0; t < 64; ++t) {
            if (ei32[2 * t + 1] != 0) { is64 = 0; break; }
        }
        *flag = is64;
    }
}

__device__ __forceinline__ int load_edge(const void* ei, int is64, int pos) {
    return is64 ? (int)((const long long*)ei)[pos] : ((const int*)ei)[pos];
}

// ---------------------------------------------------------------------------
__global__ __launch_bounds__(TPB) void count_deg_kernel(const void* __restrict__ ei, int E,
                                                        int* __restrict__ cnt,
                                                        const int* __restrict__ flag, int N) {
    int e = blockIdx.x * TPB + threadIdx.x;
    if (e >= E) return;
    int is64 = *flag;
    int r = load_edge(ei, is64, e);
    if ((unsigned)r < (unsigned)N) atomicAdd(&cnt[r], 1);
}

// ---------------------------------------------------------------------------
// scan part 1: per-1024-element tile local exclusive scan + tile totals; also dis[i]
__global__ __launch_bounds__(TPB) void scan1_kernel(const int* __restrict__ cnt,
                                                    int* __restrict__ offs,
                                                    int* __restrict__ bsums,
                                                    float* __restrict__ dis, int N) {
    __shared__ int sm[TPB];
    int tid = threadIdx.x;
    int base = blockIdx.x * 1024 + tid * 4;
    int4 v = make_int4(0, 0, 0, 0);
    if (base + 3 < N) {
        v = *(const int4*)(cnt + base);
    } else {
        if (base + 0 < N) v.x = cnt[base + 0];
        if (base + 1 < N) v.y = cnt[base + 1];
        if (base + 2 < N) v.z = cnt[base + 2];
        if (base + 3 < N) v.w = cnt[base + 3];
    }
    int tsum = v.x + v.y + v.z + v.w;
    sm[tid] = tsum;
    __syncthreads();
    for (int o = 1; o < TPB; o <<= 1) {
        int x = (tid >= o) ? sm[tid - o] : 0;
        __syncthreads();
        sm[tid] += x;
        __syncthreads();
    }
    int excl = sm[tid] - tsum;
    int4 o4;
    o4.x = excl;
    o4.y = o4.x + v.x;
    o4.z = o4.y + v.y;
    o4.w = o4.z + v.z;
    if (base + 3 < N) {
        *(int4*)(offs + base) = o4;
    } else {
        if (base + 0 < N) offs[base + 0] = o4.x;
        if (base + 1 < N) offs[base + 1] = o4.y;
        if (base + 2 < N) offs[base + 2] = o4.z;
        if (base + 3 < N) offs[base + 3] = o4.w;
    }
    if (tid == TPB - 1) bsums[blockIdx.x] = sm[TPB - 1];
    // dis = (deg+self)^{-1/2}
    int vv[4] = {v.x, v.y, v.z, v.w};
#pragma unroll
    for (int t = 0; t < 4; ++t) {
        int i = base + t;
        if (i < N) dis[i] = rsqrtf((float)vv[t] + 1.0f);
    }
}

// scan part 2: exclusive scan over tile sums (nb <= 128)
__global__ void scan2_kernel(int* __restrict__ bsums, int nb) {
    __shared__ int sm[128];
    int tid = threadIdx.x;
    int v = (tid < nb) ? bsums[tid] : 0;
    sm[tid] = v;
    __syncthreads();
    for (int o = 1; o < 128; o <<= 1) {
        int x = (tid >= o) ? sm[tid - o] : 0;
        __syncthreads();
        sm[tid] += x;
        __syncthreads();
    }
    if (tid < nb) bsums[tid] = sm[tid] - v;  // exclusive
}

// scan part 3: add tile offsets
__global__ __launch_bounds__(TPB) void scan3_kernel(int* __restrict__ offs,
                                                    const int* __restrict__ bsums, int N) {
    int add = bsums[blockIdx.x];
    int base = blockIdx.x * 1024 + threadIdx.x * 4;
    if (base + 3 < N) {
        int4 v = *(int4*)(offs + base);
        v.x += add; v.y += add; v.z += add; v.w += add;
        *(int4*)(offs + base) = v;
    } else {
#pragma unroll
        for (int t = 0; t < 4; ++t)
            if (base + t < N) offs[base + t] += add;
    }
}

// ---------------------------------------------------------------------------
__global__ __launch_bounds__(TPB) void fill_csr_kernel(const void* __restrict__ ei, int E,
                                                       const int* __restrict__ offs,
                                                       int* __restrict__ cursor,
                                                       int* __restrict__ csr,
                                                       const int* __restrict__ flag, int N) {
    int e = blockIdx.x * TPB + threadIdx.x;
    if (e >= E) return;
    int is64 = *flag;
    int r = load_edge(ei, is64, e);
    int c = load_edge(ei, is64, E + e);
    if ((unsigned)r < (unsigned)N && (unsigned)c < (unsigned)N) {
        int pos = offs[r] + atomicAdd(&cursor[r], 1);
        csr[pos] = c;
    }
}

// ---------------------------------------------------------------------------
// fp32 GEMM: H[n, j0:j0+OTILE] = dis[n] * (X[n,:] @ W[j0:j0+OTILE,:]^T + b).
// W tile transposed into LDS (padded stride); X streamed from global into registers.
template <int OTILE, int NPT, int OUTF>
__global__ __launch_bounds__(TPB) void gemm_kernel(const float* __restrict__ X,
                                                   const float* __restrict__ W,
                                                   const float* __restrict__ bias,
                                                   const float* __restrict__ dis,
                                                   float* __restrict__ H, int N) {
    constexpr int K = 128;
    constexpr int QUADS = OTILE / 4;        // 16
    constexpr int GROUPS = TPB / QUADS;     // 16
    constexpr int NPB = GROUPS * NPT;       // nodes per block
    constexpr int WST = OTILE + 4;          // padded LDS row stride (floats)
    __shared__ float Wt[K * WST];

    const int tid = threadIdx.x;
    const int j0 = blockIdx.y * OTILE;
    const float* Wsub = W + j0 * K;
    for (int idx = tid; idx < OTILE * K; idx += TPB) {
        int j = idx >> 7;      // row within tile
        int k = idx & 127;
        Wt[k * WST + j] = Wsub[idx];
    }
    __syncthreads();

    const int j4 = tid % QUADS;
    const int g = tid / QUADS;
    const int node0 = blockIdx.x * NPB + g * NPT;
    const float4* Xv = (const float4*)X;

    bool valid[NPT];
#pragma unroll
    for (int np = 0; np < NPT; ++np) valid[np] = (node0 + np) < N;

    float acc[NPT][4];
#pragma unroll
    for (int a = 0; a < NPT; ++a)
#pragma unroll
        for (int b = 0; b < 4; ++b) acc[a][b] = 0.0f;

#pragma unroll 2
    for (int k4 = 0; k4 < K / 4; ++k4) {
        float4 w0 = *(const float4*)&Wt[(4 * k4 + 0) * WST + 4 * j4];
        float4 w1 = *(const float4*)&Wt[(4 * k4 + 1) * WST + 4 * j4];
        float4 w2 = *(const float4*)&Wt[(4 * k4 + 2) * WST + 4 * j4];
        float4 w3 = *(const float4*)&Wt[(4 * k4 + 3) * WST + 4 * j4];
#pragma unroll
        for (int np = 0; np < NPT; ++np) {
            float4 xv = valid[np] ? Xv[(node0 + np) * (K / 4) + k4]
                                  : make_float4(0.f, 0.f, 0.f, 0.f);
            acc[np][0] += xv.x * w0.x + xv.y * w1.x + xv.z * w2.x + xv.w * w3.x;
            acc[np][1] += xv.x * w0.y + xv.y * w1.y + xv.z * w2.y + xv.w * w3.y;
            acc[np][2] += xv.x * w0.z + xv.y * w1.z + xv.z * w2.z + xv.w * w3.z;
            acc[np][3] += xv.x * w0.w + xv.y * w1.w + xv.z * w2.w + xv.w * w3.w;
        }
    }

    const float4 bv = *(const float4*)&bias[j0 + 4 * j4];
#pragma unroll
    for (int np = 0; np < NPT; ++np) {
        int node = node0 + np;
        if (node < N) {
            float dn = dis[node];
            float4 r = make_float4((acc[np][0] + bv.x) * dn, (acc[np][1] + bv.y) * dn,
                                   (acc[np][2] + bv.z) * dn, (acc[np][3] + bv.w) * dn);
            ((float4*)H)[node * (OUTF / 4) + (j0 >> 2) + j4] = r;
        }
    }
}

// ---------------------------------------------------------------------------
// Pull aggregation over pre-scaled H' (H'[n] = dis[n]*(XW+b)[n]):
//   out[i] = dis[i] * (H'[i] + sum_e H'[col_e]),  optional relu.
// One wave per node. Edge indices fetched coalesced 64-at-a-time, broadcast
// via shfl; the only in-loop global op is the H row gather, 8-way unrolled.
template <int F, bool RELU>
__global__ __launch_bounds__(TPB) void agg_kernel(const float* __restrict__ H,
                                                  const int* __restrict__ csr,
                                                  const int* __restrict__ offs,
                                                  const int* __restrict__ cnt,
                                                  const float* __restrict__ dis,
                                                  float* __restrict__ out, int N) {
    int w = (blockIdx.x * TPB + threadIdx.x) >> 6;
    if (w >= N) return;  // wave-uniform: whole wave exits together
    int lane = threadIdx.x & 63;
    float di = dis[w];
    int s = offs[w];
    int d = cnt[w];

    const float2* Hp2 = (const float2*)H;
    float2 acc;
    if (F == 128) {
        acc = Hp2[w * 64 + lane];
    } else {
        acc.x = H[w * 64 + lane];
        acc.y = 0.0f;
    }

    for (int base = 0; base < d; base += 64) {
        int rem = d - base;
        if (rem > 64) rem = 64;
        int cl = (lane < rem) ? csr[s + base + lane] : 0;  // coalesced chunk load

        int e = 0;
        for (; e + 8 <= rem; e += 8) {
            int c0 = __shfl(cl, e + 0);
            int c1 = __shfl(cl, e + 1);
            int c2 = __shfl(cl, e + 2);
            int c3 = __shfl(cl, e + 3);
            int c4 = __shfl(cl, e + 4);
            int c5 = __shfl(cl, e + 5);
            int c6 = __shfl(cl, e + 6);
            int c7 = __shfl(cl, e + 7);
            if (F == 128) {
                float2 h0 = Hp2[c0 * 64 + lane];
                float2 h1 = Hp2[c1 * 64 + lane];
                float2 h2 = Hp2[c2 * 64 + lane];
                float2 h3 = Hp2[c3 * 64 + lane];
                float2 h4 = Hp2[c4 * 64 + lane];
                float2 h5 = Hp2[c5 * 64 + lane];
                float2 h6 = Hp2[c6 * 64 + lane];
                float2 h7 = Hp2[c7 * 64 + lane];
                acc.x += ((h0.x + h1.x) + (h2.x + h3.x)) + ((h4.x + h5.x) + (h6.x + h7.x));
                acc.y += ((h0.y + h1.y) + (h2.y + h3.y)) + ((h4.y + h5.y) + (h6.y + h7.y));
            } else {
                float h0 = H[c0 * 64 + lane];
                float h1 = H[c1 * 64 + lane];
                float h2 = H[c2 * 64 + lane];
                float h3 = H[c3 * 64 + lane];
                float h4 = H[c4 * 64 + lane];
                float h5 = H[c5 * 64 + lane];
                float h6 = H[c6 * 64 + lane];
                float h7 = H[c7 * 64 + lane];
                acc.x += ((h0 + h1) + (h2 + h3)) + ((h4 + h5) + (h6 + h7));
            }
        }
        for (; e < rem; ++e) {
            int c0 = __shfl(cl, e);
            if (F == 128) {
                float2 h0 = Hp2[c0 * 64 + lane];
                acc.x += h0.x;
                acc.y += h0.y;
            } else {
                acc.x += H[c0 * 64 + lane];
            }
        }
    }

    acc.x *= di;
    acc.y *= di;
    if (RELU) { acc.x = fmaxf(acc.x, 0.f); acc.y = fmaxf(acc.y, 0.f); }
    if (F == 128) {
        ((float2*)out)[w * 64 + lane] = acc;
    } else {
        out[w * 64 + lane] = acc.x;
    }
}

// ---------------------------------------------------------------------------
extern "C" void kernel_launch(void* const* d_in, const int* in_sizes, int n_in,
                              void* d_out, int out_size, void* d_ws, size_t ws_size,
                              hipStream_t stream) {
    const float* x  = (const float*)d_in[0];
    const void*  ei = d_in[1];
    const float* W1 = (const float*)d_in[3];
    const float* b1 = (const float*)d_in[4];
    const float* W2 = (const float*)d_in[5];
    const float* b2 = (const float*)d_in[6];
    float* out = (float*)d_out;

    const int IN = 128, HID = 128, OUT = 64;
    const int N = in_sizes[0] / IN;
    const int E = in_sizes[1] / 2;

    char* ws = (char*)d_ws;
    size_t off = 0;
    auto alloc = [&](size_t bytes) -> void* {
        void* p = (void*)(ws + off);
        off += (bytes + 255) & ~(size_t)255;
        return p;
    };
    int*   cnt    = (int*)alloc((size_t)N * 4);
    int*   cursor = (int*)alloc((size_t)N * 4);
    int*   offs   = (int*)alloc((size_t)N * 4);
    int*   bsums  = (int*)alloc(512);
    int*   flag   = (int*)alloc(256);
    float* dis    = (float*)alloc((size_t)N * 4);
    int*   csr    = (int*)alloc((size_t)E * 4);
    float* H1     = (float*)alloc((size_t)N * HID * 4);
    float* R1     = (float*)alloc((size_t)N * HID * 4);
    float* H2     = H1;  // reuse: H1 dead after agg1

    hipMemsetAsync(cnt, 0, (size_t)N * 4, stream);
    hipMemsetAsync(cursor, 0, (size_t)N * 4, stream);

    detect64_kernel<<<1, 64, 0, stream>>>((const int*)ei, flag);

    int egrid = (E + TPB - 1) / TPB;
    count_deg_kernel<<<egrid, TPB, 0, stream>>>(ei, E, cnt, flag, N);

    int nb = (N + 1023) / 1024;
    scan1_kernel<<<nb, TPB, 0, stream>>>(cnt, offs, bsums, dis, N);
    scan2_kernel<<<1, 128, 0, stream>>>(bsums, nb);
    scan3_kernel<<<nb, TPB, 0, stream>>>(offs, bsums, N);

    fill_csr_kernel<<<egrid, TPB, 0, stream>>>(ei, E, offs, cursor, csr, flag, N);

    // layer 1: H1 = dis .* (X@W1^T + b1) ; R1 = relu(dis .* (H1[self] + gather))
    {
        dim3 grid((N + 63) / 64, HID / 64);
        gemm_kernel<64, 4, 128><<<grid, TPB, 0, stream>>>(x, W1, b1, dis, H1, N);
    }
    agg_kernel<128, true><<<(N + 3) / 4, TPB, 0, stream>>>(H1, csr, offs, cnt, dis, R1, N);

    // layer 2: H2 = dis .* (R1@W2^T + b2) ; out = dis .* (H2[self] + gather)
    {
        dim3 grid((N + 63) / 64, OUT / 64);
        gemm_kernel<64, 4, 64><<<grid, TPB, 0, stream>>>(R1, W2, b2, dis, H2, N);
    }
    agg_kernel<64, false><<<(N + 3) / 4, TPB, 0, stream>>>(H2, csr, offs, cnt, dis, out, N);
}

// Round 3
// 522.332 us; speedup vs baseline: 1.4828x; 1.1729x over previous
//
#include <hip/hip_runtime.h>
#include <hip/hip_bf16.h>
#include <stdint.h>

// GCN 2-layer forward: out = A_hat @ relu(A_hat @ (X W1^T + b1)) W2^T + b2
// A_hat = D^-1/2 (A + I) D^-1/2, pull-based CSR aggregation (no fp32 atomics).
// GEMM epilogue pre-scales rows by dis[n], so aggregation is
// out[i] = dis[i] * (H'[i] + sum_e H'[col]) — edge loop is gather+add only.

#define TPB 256

// ---------------------------------------------------------------------------
// dtype probe: edge_index may arrive as int32 or int64. If int64 (values < 2^31,
// non-negative), every odd 32-bit word of the first 64 entries is 0.
__global__ void detect64_kernel(const int* __restrict__ ei32, int* __restrict__ flag) {
    if (threadIdx.x == 0 && blockIdx.x == 0) {
        int is64 = 1;
        for (int t = 0; t < 64; ++t) {
            if (ei32[2 * t + 1] != 0) { is64 = 0; break; }
        }
        *flag = is64;
    }
}

__device__ __forceinline__ int load_edge(const void* ei, int is64, int pos) {
    return is64 ? (int)((const long long*)ei)[pos] : ((const int*)ei)[pos];
}

// ---------------------------------------------------------------------------
__global__ __launch_bounds__(TPB) void count_deg_kernel(const void* __restrict__ ei, int E,
                                                        int* __restrict__ cnt,
                                                        const int* __restrict__ flag, int N) {
    int e = blockIdx.x * TPB + threadIdx.x;
    if (e >= E) return;
    int is64 = *flag;
    int r = load_edge(ei, is64, e);
    if ((unsigned)r < (unsigned)N) atomicAdd(&cnt[r], 1);
}

// ---------------------------------------------------------------------------
// scan part 1: per-1024-element tile local exclusive scan + tile totals; also dis[i]
__global__ __launch_bounds__(TPB) void scan1_kernel(const int* __restrict__ cnt,
                                                    int* __restrict__ offs,
                                                    int* __restrict__ bsums,
                                                    float* __restrict__ dis, int N) {
    __shared__ int sm[TPB];
    int tid = threadIdx.x;
    int base = blockIdx.x * 1024 + tid * 4;
    int4 v = make_int4(0, 0, 0, 0);
    if (base + 3 < N) {
        v = *(const int4*)(cnt + base);
    } else {
        if (base + 0 < N) v.x = cnt[base + 0];
        if (base + 1 < N) v.y = cnt[base + 1];
        if (base + 2 < N) v.z = cnt[base + 2];
        if (base + 3 < N) v.w = cnt[base + 3];
    }
    int tsum = v.x + v.y + v.z + v.w;
    sm[tid] = tsum;
    __syncthreads();
    for (int o = 1; o < TPB; o <<= 1) {
        int x = (tid >= o) ? sm[tid - o] : 0;
        __syncthreads();
        sm[tid] += x;
        __syncthreads();
    }
    int excl = sm[tid] - tsum;
    int4 o4;
    o4.x = excl;
    o4.y = o4.x + v.x;
    o4.z = o4.y + v.y;
    o4.w = o4.z + v.z;
    if (base + 3 < N) {
        *(int4*)(offs + base) = o4;
    } else {
        if (base + 0 < N) offs[base + 0] = o4.x;
        if (base + 1 < N) offs[base + 1] = o4.y;
        if (base + 2 < N) offs[base + 2] = o4.z;
        if (base + 3 < N) offs[base + 3] = o4.w;
    }
    if (tid == TPB - 1) bsums[blockIdx.x] = sm[TPB - 1];
    // dis = (deg+self)^{-1/2}
    int vv[4] = {v.x, v.y, v.z, v.w};
#pragma unroll
    for (int t = 0; t < 4; ++t) {
        int i = base + t;
        if (i < N) dis[i] = rsqrtf((float)vv[t] + 1.0f);
    }
}

// scan part 2: exclusive scan over tile sums (nb <= 128)
__global__ void scan2_kernel(int* __restrict__ bsums, int nb) {
    __shared__ int sm[128];
    int tid = threadIdx.x;
    int v = (tid < nb) ? bsums[tid] : 0;
    sm[tid] = v;
    __syncthreads();
    for (int o = 1; o < 128; o <<= 1) {
        int x = (tid >= o) ? sm[tid - o] : 0;
        __syncthreads();
        sm[tid] += x;
        __syncthreads();
    }
    if (tid < nb) bsums[tid] = sm[tid] - v;  // exclusive
}

// scan part 3: add tile offsets
__global__ __launch_bounds__(TPB) void scan3_kernel(int* __restrict__ offs,
                                                    const int* __restrict__ bsums, int N) {
    int add = bsums[blockIdx.x];
    int base = blockIdx.x * 1024 + threadIdx.x * 4;
    if (base + 3 < N) {
        int4 v = *(int4*)(offs + base);
        v.x += add; v.y += add; v.z += add; v.w += add;
        *(int4*)(offs + base) = v;
    } else {
#pragma unroll
        for (int t = 0; t < 4; ++t)
            if (base + t < N) offs[base + t] += add;
    }
}

// ---------------------------------------------------------------------------
__global__ __launch_bounds__(TPB) void fill_csr_kernel(const void* __restrict__ ei, int E,
                                                       const int* __restrict__ offs,
                                                       int* __restrict__ cursor,
                                                       int* __restrict__ csr,
                                                       const int* __restrict__ flag, int N) {
    int e = blockIdx.x * TPB + threadIdx.x;
    if (e >= E) return;
    int is64 = *flag;
    int r = load_edge(ei, is64, e);
    int c = load_edge(ei, is64, E + e);
    if ((unsigned)r < (unsigned)N && (unsigned)c < (unsigned)N) {
        int pos = offs[r] + atomicAdd(&cursor[r], 1);
        csr[pos] = c;
    }
}

// ---------------------------------------------------------------------------
// Tiled fp32 GEMM: H[r, :] = dis[r] * (X[r,:] @ W^T + b),  K = 128, BN == OUTF.
// BM=128 nodes/block, BK=32. Both operands staged (transposed) in LDS; X read
// from global exactly once. 256 threads as 16x16; micro-tile 8 rows x (BN/16)
// cols per thread. W-col split {4tx, 64+4tx} keeps LDS reads 2-way (free).
template <int BN>
__global__ __launch_bounds__(256, 4) void gemm_tiled_kernel(const float* __restrict__ X,
                                                            const float* __restrict__ W,
                                                            const float* __restrict__ bias,
                                                            const float* __restrict__ dis,
                                                            float* __restrict__ H, int N) {
    constexpr int BM = 128, BK = 32, K = 128;
    constexpr int BMp = BM + 4;          // 132 (float4-aligned rows, staggers writes)
    constexpr int BNp = BN + 4;
    constexpr int CN = BN / 16;          // cols per thread: 8 (BN=128) or 4 (BN=64)
    __shared__ float Xs[BK * BMp];
    __shared__ float Ws[BK * BNp];

    const int tid = threadIdx.x;
    const int tx = tid & 15;             // col group
    const int ty = tid >> 4;             // row group
    const int r0 = blockIdx.x * BM;
    const int lrow = tid >> 3;           // 0..31 (staging row)
    const int kq = tid & 7;              // 0..7  (staging k-quad)

    float acc[8][CN];
#pragma unroll
    for (int r = 0; r < 8; ++r)
#pragma unroll
        for (int c = 0; c < CN; ++c) acc[r][c] = 0.0f;

    const float4* Xv = (const float4*)X;
    const float4* Wv = (const float4*)W;

    for (int k0 = 0; k0 < K; k0 += BK) {
        // ---- stage X tile (BM x BK), transposed to Xs[k][m]
#pragma unroll
        for (int p = 0; p < BM / 32; ++p) {
            int row = lrow + p * 32;
            int rg = r0 + row;
            if (rg >= N) rg = N - 1;     // clamp (stores are guarded)
            float4 v = Xv[(size_t)rg * (K / 4) + (k0 >> 2) + kq];
            Xs[(4 * kq + 0) * BMp + row] = v.x;
            Xs[(4 * kq + 1) * BMp + row] = v.y;
            Xs[(4 * kq + 2) * BMp + row] = v.z;
            Xs[(4 * kq + 3) * BMp + row] = v.w;
        }
        // ---- stage W tile (BN x BK), transposed to Ws[k][n]
#pragma unroll
        for (int p = 0; p < BN / 32; ++p) {
            int j = lrow + p * 32;
            float4 v = Wv[(size_t)j * (K / 4) + (k0 >> 2) + kq];
            Ws[(4 * kq + 0) * BNp + j] = v.x;
            Ws[(4 * kq + 1) * BNp + j] = v.y;
            Ws[(4 * kq + 2) * BNp + j] = v.z;
            Ws[(4 * kq + 3) * BNp + j] = v.w;
        }
        __syncthreads();

#pragma unroll 4
        for (int k = 0; k < BK; ++k) {
            float4 xa = *(const float4*)&Xs[k * BMp + 8 * ty];
            float4 xb = *(const float4*)&Xs[k * BMp + 8 * ty + 4];
            float4 wa = *(const float4*)&Ws[k * BNp + 4 * tx];
            float xr[8] = {xa.x, xa.y, xa.z, xa.w, xb.x, xb.y, xb.z, xb.w};
            float wc[CN];
            wc[0] = wa.x; wc[1] = wa.y; wc[2] = wa.z; wc[3] = wa.w;
            if (BN == 128) {
                float4 wb = *(const float4*)&Ws[k * BNp + 64 + 4 * tx];
                wc[4] = wb.x; wc[5] = wb.y; wc[6] = wb.z; wc[7] = wb.w;
            }
#pragma unroll
            for (int r = 0; r < 8; ++r)
#pragma unroll
                for (int c = 0; c < CN; ++c) acc[r][c] += xr[r] * wc[c];
        }
        __syncthreads();
    }

    // ---- epilogue: (+bias) * dis[row], store float4s
    float4 bva = *(const float4*)&bias[4 * tx];
    float4 bvb = make_float4(0.f, 0.f, 0.f, 0.f);
    if (BN == 128) bvb = *(const float4*)&bias[64 + 4 * tx];
#pragma unroll
    for (int r = 0; r < 8; ++r) {
        int row = r0 + 8 * ty + r;
        if (row < N) {
            float dn = dis[row];
            float4 oa = make_float4((acc[r][0] + bva.x) * dn, (acc[r][1] + bva.y) * dn,
                                    (acc[r][2] + bva.z) * dn, (acc[r][3] + bva.w) * dn);
            ((float4*)H)[(size_t)row * (BN / 4) + tx] = oa;
            if (BN == 128) {
                float4 ob = make_float4((acc[r][4] + bvb.x) * dn, (acc[r][5] + bvb.y) * dn,
                                        (acc[r][6] + bvb.z) * dn, (acc[r][7] + bvb.w) * dn);
                ((float4*)H)[(size_t)row * (BN / 4) + 16 + tx] = ob;
            }
        }
    }
}

// ---------------------------------------------------------------------------
// Pull aggregation over pre-scaled H' (H'[n] = dis[n]*(XW+b)[n]):
//   out[i] = dis[i] * (H'[i] + sum_e H'[col_e]),  optional relu.
// One wave per node. Edge indices fetched coalesced 64-at-a-time, broadcast
// via shfl; the only in-loop global op is the H row gather, 8-way unrolled.
template <int F, bool RELU>
__global__ __launch_bounds__(TPB) void agg_kernel(const float* __restrict__ H,
                                                  const int* __restrict__ csr,
                                                  const int* __restrict__ offs,
                                                  const int* __restrict__ cnt,
                                                  const float* __restrict__ dis,
                                                  float* __restrict__ out, int N) {
    int w = (blockIdx.x * TPB + threadIdx.x) >> 6;
    if (w >= N) return;  // wave-uniform: whole wave exits together
    int lane = threadIdx.x & 63;
    float di = dis[w];
    int s = offs[w];
    int d = cnt[w];

    const float2* Hp2 = (const float2*)H;
    float2 acc;
    if (F == 128) {
        acc = Hp2[w * 64 + lane];
    } else {
        acc.x = H[w * 64 + lane];
        acc.y = 0.0f;
    }

    for (int base = 0; base < d; base += 64) {
        int rem = d - base;
        if (rem > 64) rem = 64;
        int cl = (lane < rem) ? csr[s + base + lane] : 0;  // coalesced chunk load

        int e = 0;
        for (; e + 8 <= rem; e += 8) {
            int c0 = __shfl(cl, e + 0);
            int c1 = __shfl(cl, e + 1);
            int c2 = __shfl(cl, e + 2);
            int c3 = __shfl(cl, e + 3);
            int c4 = __shfl(cl, e + 4);
            int c5 = __shfl(cl, e + 5);
            int c6 = __shfl(cl, e + 6);
            int c7 = __shfl(cl, e + 7);
            if (F == 128) {
                float2 h0 = Hp2[c0 * 64 + lane];
                float2 h1 = Hp2[c1 * 64 + lane];
                float2 h2 = Hp2[c2 * 64 + lane];
                float2 h3 = Hp2[c3 * 64 + lane];
                float2 h4 = Hp2[c4 * 64 + lane];
                float2 h5 = Hp2[c5 * 64 + lane];
                float2 h6 = Hp2[c6 * 64 + lane];
                float2 h7 = Hp2[c7 * 64 + lane];
                acc.x += ((h0.x + h1.x) + (h2.x + h3.x)) + ((h4.x + h5.x) + (h6.x + h7.x));
                acc.y += ((h0.y + h1.y) + (h2.y + h3.y)) + ((h4.y + h5.y) + (h6.y + h7.y));
            } else {
                float h0 = H[c0 * 64 + lane];
                float h1 = H[c1 * 64 + lane];
                float h2 = H[c2 * 64 + lane];
                float h3 = H[c3 * 64 + lane];
                float h4 = H[c4 * 64 + lane];
                float h5 = H[c5 * 64 + lane];
                float h6 = H[c6 * 64 + lane];
                float h7 = H[c7 * 64 + lane];
                acc.x += ((h0 + h1) + (h2 + h3)) + ((h4 + h5) + (h6 + h7));
            }
        }
        for (; e < rem; ++e) {
            int c0 = __shfl(cl, e);
            if (F == 128) {
                float2 h0 = Hp2[c0 * 64 + lane];
                acc.x += h0.x;
                acc.y += h0.y;
            } else {
                acc.x += H[c0 * 64 + lane];
            }
        }
    }

    acc.x *= di;
    acc.y *= di;
    if (RELU) { acc.x = fmaxf(acc.x, 0.f); acc.y = fmaxf(acc.y, 0.f); }
    if (F == 128) {
        ((float2*)out)[w * 64 + lane] = acc;
    } else {
        out[w * 64 + lane] = acc.x;
    }
}

// ---------------------------------------------------------------------------
extern "C" void kernel_launch(void* const* d_in, const int* in_sizes, int n_in,
                              void* d_out, int out_size, void* d_ws, size_t ws_size,
                              hipStream_t stream) {
    const float* x  = (const float*)d_in[0];
    const void*  ei = d_in[1];
    const float* W1 = (const float*)d_in[3];
    const float* b1 = (const float*)d_in[4];
    const float* W2 = (const float*)d_in[5];
    const float* b2 = (const float*)d_in[6];
    float* out = (float*)d_out;

    const int IN = 128, HID = 128, OUT = 64;
    const int N = in_sizes[0] / IN;
    const int E = in_sizes[1] / 2;

    char* ws = (char*)d_ws;
    size_t off = 0;
    auto alloc = [&](size_t bytes) -> void* {
        void* p = (void*)(ws + off);
        off += (bytes + 255) & ~(size_t)255;
        return p;
    };
    int*   cnt    = (int*)alloc((size_t)N * 4);
    int*   cursor = (int*)alloc((size_t)N * 4);
    int*   offs   = (int*)alloc((size_t)N * 4);
    int*   bsums  = (int*)alloc(512);
    int*   flag   = (int*)alloc(256);
    float* dis    = (float*)alloc((size_t)N * 4);
    int*   csr    = (int*)alloc((size_t)E * 4);
    float* H1     = (float*)alloc((size_t)N * HID * 4);
    float* R1     = (float*)alloc((size_t)N * HID * 4);
    float* H2     = H1;  // reuse: H1 dead after agg1

    hipMemsetAsync(cnt, 0, (size_t)N * 4, stream);
    hipMemsetAsync(cursor, 0, (size_t)N * 4, stream);

    detect64_kernel<<<1, 64, 0, stream>>>((const int*)ei, flag);

    int egrid = (E + TPB - 1) / TPB;
    count_deg_kernel<<<egrid, TPB, 0, stream>>>(ei, E, cnt, flag, N);

    int nb = (N + 1023) / 1024;
    scan1_kernel<<<nb, TPB, 0, stream>>>(cnt, offs, bsums, dis, N);
    scan2_kernel<<<1, 128, 0, stream>>>(bsums, nb);
    scan3_kernel<<<nb, TPB, 0, stream>>>(offs, bsums, N);

    fill_csr_kernel<<<egrid, TPB, 0, stream>>>(ei, E, offs, cursor, csr, flag, N);

    int ngrid = (N + 127) / 128;

    // layer 1: H1 = dis .* (X@W1^T + b1) ; R1 = relu(dis .* (H1[self] + gather))
    gemm_tiled_kernel<128><<<ngrid, 256, 0, stream>>>(x, W1, b1, dis, H1, N);
    agg_kernel<128, true><<<(N + 3) / 4, TPB, 0, stream>>>(H1, csr, offs, cnt, dis, R1, N);

    // layer 2: H2 = dis .* (R1@W2^T + b2) ; out = dis .* (H2[self] + gather)
    gemm_tiled_kernel<64><<<ngrid, 256, 0, stream>>>(R1, W2, b2, dis, H2, N);
    agg_kernel<64, false><<<(N + 3) / 4, TPB, 0, stream>>>(H2, csr, offs, cnt, dis, out, N);
}

// Round 4
// 480.991 us; speedup vs baseline: 1.6103x; 1.0860x over previous
//
#include <hip/hip_runtime.h>
#include <hip/hip_bf16.h>
#include <stdint.h>

// GCN 2-layer forward: out = A_hat @ relu(A_hat @ (X W1^T + b1)) W2^T + b2
// A_hat = D^-1/2 (A + I) D^-1/2, pull-based CSR aggregation (no fp32 atomics).
// GEMM epilogue pre-scales rows by dis[n] and stores H' in BF16 (halves gather
// bytes); aggregation gathers bf16, accumulates fp32:
//   out[i] = dis[i] * (H'[i] + sum_e H'[col]).  R1 kept fp32 for gemm2 input.

#define TPB 256

__device__ __forceinline__ float bf16lo(unsigned u) { return __uint_as_float(u << 16); }
__device__ __forceinline__ float bf16hi(unsigned u) { return __uint_as_float(u & 0xffff0000u); }
__device__ __forceinline__ unsigned short f2bf(float f) {
    unsigned u = __float_as_uint(f);
    return (unsigned short)((u + 0x7fff + ((u >> 16) & 1)) >> 16);  // RNE
}

// ---------------------------------------------------------------------------
// dtype probe: edge_index may arrive as int32 or int64. If int64 (values < 2^31,
// non-negative), every odd 32-bit word of the first 64 entries is 0.
__global__ void detect64_kernel(const int* __restrict__ ei32, int* __restrict__ flag) {
    if (threadIdx.x == 0 && blockIdx.x == 0) {
        int is64 = 1;
        for (int t = 0; t < 64; ++t) {
            if (ei32[2 * t + 1] != 0) { is64 = 0; break; }
        }
        *flag = is64;
    }
}

__device__ __forceinline__ int load_edge(const void* ei, int is64, int pos) {
    return is64 ? (int)((const long long*)ei)[pos] : ((const int*)ei)[pos];
}

// ---------------------------------------------------------------------------
__global__ __launch_bounds__(TPB) void count_deg_kernel(const void* __restrict__ ei, int E,
                                                        int* __restrict__ cnt,
                                                        const int* __restrict__ flag, int N) {
    int e = blockIdx.x * TPB + threadIdx.x;
    if (e >= E) return;
    int is64 = *flag;
    int r = load_edge(ei, is64, e);
    if ((unsigned)r < (unsigned)N) atomicAdd(&cnt[r], 1);
}

// ---------------------------------------------------------------------------
// scan part 1: per-1024-element tile local exclusive scan + tile totals; also dis[i]
__global__ __launch_bounds__(TPB) void scan1_kernel(const int* __restrict__ cnt,
                                                    int* __restrict__ offs,
                                                    int* __restrict__ bsums,
                                                    float* __restrict__ dis, int N) {
    __shared__ int sm[TPB];
    int tid = threadIdx.x;
    int base = blockIdx.x * 1024 + tid * 4;
    int4 v = make_int4(0, 0, 0, 0);
    if (base + 3 < N) {
        v = *(const int4*)(cnt + base);
    } else {
        if (base + 0 < N) v.x = cnt[base + 0];
        if (base + 1 < N) v.y = cnt[base + 1];
        if (base + 2 < N) v.z = cnt[base + 2];
        if (base + 3 < N) v.w = cnt[base + 3];
    }
    int tsum = v.x + v.y + v.z + v.w;
    sm[tid] = tsum;
    __syncthreads();
    for (int o = 1; o < TPB; o <<= 1) {
        int x = (tid >= o) ? sm[tid - o] : 0;
        __syncthreads();
        sm[tid] += x;
        __syncthreads();
    }
    int excl = sm[tid] - tsum;
    int4 o4;
    o4.x = excl;
    o4.y = o4.x + v.x;
    o4.z = o4.y + v.y;
    o4.w = o4.z + v.z;
    if (base + 3 < N) {
        *(int4*)(offs + base) = o4;
    } else {
        if (base + 0 < N) offs[base + 0] = o4.x;
        if (base + 1 < N) offs[base + 1] = o4.y;
        if (base + 2 < N) offs[base + 2] = o4.z;
        if (base + 3 < N) offs[base + 3] = o4.w;
    }
    if (tid == TPB - 1) bsums[blockIdx.x] = sm[TPB - 1];
    // dis = (deg+self)^{-1/2}
    int vv[4] = {v.x, v.y, v.z, v.w};
#pragma unroll
    for (int t = 0; t < 4; ++t) {
        int i = base + t;
        if (i < N) dis[i] = rsqrtf((float)vv[t] + 1.0f);
    }
}

// scan part 2: exclusive scan over tile sums (nb <= 128)
__global__ void scan2_kernel(int* __restrict__ bsums, int nb) {
    __shared__ int sm[128];
    int tid = threadIdx.x;
    int v = (tid < nb) ? bsums[tid] : 0;
    sm[tid] = v;
    __syncthreads();
    for (int o = 1; o < 128; o <<= 1) {
        int x = (tid >= o) ? sm[tid - o] : 0;
        __syncthreads();
        sm[tid] += x;
        __syncthreads();
    }
    if (tid < nb) bsums[tid] = sm[tid] - v;  // exclusive
}

// scan part 3: add tile offsets
__global__ __launch_bounds__(TPB) void scan3_kernel(int* __restrict__ offs,
                                                    const int* __restrict__ bsums, int N) {
    int add = bsums[blockIdx.x];
    int base = blockIdx.x * 1024 + threadIdx.x * 4;
    if (base + 3 < N) {
        int4 v = *(int4*)(offs + base);
        v.x += add; v.y += add; v.z += add; v.w += add;
        *(int4*)(offs + base) = v;
    } else {
#pragma unroll
        for (int t = 0; t < 4; ++t)
            if (base + t < N) offs[base + t] += add;
    }
}

// ---------------------------------------------------------------------------
__global__ __launch_bounds__(TPB) void fill_csr_kernel(const void* __restrict__ ei, int E,
                                                       const int* __restrict__ offs,
                                                       int* __restrict__ cursor,
                                                       int* __restrict__ csr,
                                                       const int* __restrict__ flag, int N) {
    int e = blockIdx.x * TPB + threadIdx.x;
    if (e >= E) return;
    int is64 = *flag;
    int r = load_edge(ei, is64, e);
    int c = load_edge(ei, is64, E + e);
    if ((unsigned)r < (unsigned)N && (unsigned)c < (unsigned)N) {
        int pos = offs[r] + atomicAdd(&cursor[r], 1);
        csr[pos] = c;
    }
}

// ---------------------------------------------------------------------------
// Tiled fp32 GEMM: H[r, :] = dis[r] * (X[r,:] @ W^T + b),  K = 128, BN == OUTF.
// BM=128 nodes/block, BK=32. Both operands staged (transposed) in LDS; X read
// from global exactly once. 256 threads as 16x16; micro-tile 8 rows x (BN/16)
// cols per thread. Output stored as BF16 (row-major, BN cols).
template <int BN>
__global__ __launch_bounds__(256, 4) void gemm_tiled_kernel(const float* __restrict__ X,
                                                            const float* __restrict__ W,
                                                            const float* __restrict__ bias,
                                                            const float* __restrict__ dis,
                                                            unsigned short* __restrict__ Hb,
                                                            int N) {
    constexpr int BM = 128, BK = 32, K = 128;
    constexpr int BMp = BM + 4;          // padded LDS row stride
    constexpr int BNp = BN + 4;
    constexpr int CN = BN / 16;          // cols per thread: 8 (BN=128) or 4 (BN=64)
    __shared__ float Xs[BK * BMp];
    __shared__ float Ws[BK * BNp];

    const int tid = threadIdx.x;
    const int tx = tid & 15;             // col group
    const int ty = tid >> 4;             // row group
    const int r0 = blockIdx.x * BM;
    const int lrow = tid >> 3;           // 0..31 (staging row)
    const int kq = tid & 7;              // 0..7  (staging k-quad)

    float acc[8][CN];
#pragma unroll
    for (int r = 0; r < 8; ++r)
#pragma unroll
        for (int c = 0; c < CN; ++c) acc[r][c] = 0.0f;

    const float4* Xv = (const float4*)X;
    const float4* Wv = (const float4*)W;

    for (int k0 = 0; k0 < K; k0 += BK) {
        // ---- stage X tile (BM x BK), transposed to Xs[k][m]
#pragma unroll
        for (int p = 0; p < BM / 32; ++p) {
            int row = lrow + p * 32;
            int rg = r0 + row;
            if (rg >= N) rg = N - 1;     // clamp (stores are guarded)
            float4 v = Xv[(size_t)rg * (K / 4) + (k0 >> 2) + kq];
            Xs[(4 * kq + 0) * BMp + row] = v.x;
            Xs[(4 * kq + 1) * BMp + row] = v.y;
            Xs[(4 * kq + 2) * BMp + row] = v.z;
            Xs[(4 * kq + 3) * BMp + row] = v.w;
        }
        // ---- stage W tile (BN x BK), transposed to Ws[k][n]
#pragma unroll
        for (int p = 0; p < BN / 32; ++p) {
            int j = lrow + p * 32;
            float4 v = Wv[(size_t)j * (K / 4) + (k0 >> 2) + kq];
            Ws[(4 * kq + 0) * BNp + j] = v.x;
            Ws[(4 * kq + 1) * BNp + j] = v.y;
            Ws[(4 * kq + 2) * BNp + j] = v.z;
            Ws[(4 * kq + 3) * BNp + j] = v.w;
        }
        __syncthreads();

#pragma unroll 4
        for (int k = 0; k < BK; ++k) {
            float4 xa = *(const float4*)&Xs[k * BMp + 8 * ty];
            float4 xb = *(const float4*)&Xs[k * BMp + 8 * ty + 4];
            float4 wa = *(const float4*)&Ws[k * BNp + 4 * tx];
            float xr[8] = {xa.x, xa.y, xa.z, xa.w, xb.x, xb.y, xb.z, xb.w};
            float wc[CN];
            wc[0] = wa.x; wc[1] = wa.y; wc[2] = wa.z; wc[3] = wa.w;
            if (BN == 128) {
                float4 wb = *(const float4*)&Ws[k * BNp + 64 + 4 * tx];
                wc[4] = wb.x; wc[5] = wb.y; wc[6] = wb.z; wc[7] = wb.w;
            }
#pragma unroll
            for (int r = 0; r < 8; ++r)
#pragma unroll
                for (int c = 0; c < CN; ++c) acc[r][c] += xr[r] * wc[c];
        }
        __syncthreads();
    }

    // ---- epilogue: (+bias) * dis[row], pack bf16, store ushort4 per 4 cols
    float4 bva = *(const float4*)&bias[4 * tx];
    float4 bvb = make_float4(0.f, 0.f, 0.f, 0.f);
    if (BN == 128) bvb = *(const float4*)&bias[64 + 4 * tx];
#pragma unroll
    for (int r = 0; r < 8; ++r) {
        int row = r0 + 8 * ty + r;
        if (row < N) {
            float dn = dis[row];
            ushort4 oa;
            oa.x = f2bf((acc[r][0] + bva.x) * dn);
            oa.y = f2bf((acc[r][1] + bva.y) * dn);
            oa.z = f2bf((acc[r][2] + bva.z) * dn);
            oa.w = f2bf((acc[r][3] + bva.w) * dn);
            *(ushort4*)&Hb[(size_t)row * BN + 4 * tx] = oa;
            if (BN == 128) {
                ushort4 ob;
                ob.x = f2bf((acc[r][4] + bvb.x) * dn);
                ob.y = f2bf((acc[r][5] + bvb.y) * dn);
                ob.z = f2bf((acc[r][6] + bvb.z) * dn);
                ob.w = f2bf((acc[r][7] + bvb.w) * dn);
                *(ushort4*)&Hb[(size_t)row * BN + 64 + 4 * tx] = ob;
            }
        }
    }
}

// ---------------------------------------------------------------------------
// Pull aggregation over pre-scaled bf16 H' (H'[n] = dis[n]*(XW+b)[n]):
//   out[i] = dis[i] * (H'[i] + sum_e H'[col_e]),  optional relu.  fp32 out.
// One wave per node. Edge indices fetched coalesced 64-at-a-time, broadcast
// via shfl; in-loop global op is the bf16 H row gather, 8-way unrolled.
// F=128: lane loads uint (2 bf16) -> row = 256 B.  F=64: lane loads ushort.
template <int F, bool RELU>
__global__ __launch_bounds__(TPB) void agg_kernel(const unsigned short* __restrict__ Hb,
                                                  const int* __restrict__ csr,
                                                  const int* __restrict__ offs,
                                                  const int* __restrict__ cnt,
                                                  const float* __restrict__ dis,
                                                  float* __restrict__ out, int N) {
    int w = (blockIdx.x * TPB + threadIdx.x) >> 6;
    if (w >= N) return;  // wave-uniform: whole wave exits together
    int lane = threadIdx.x & 63;
    float di = dis[w];
    int s = offs[w];
    int d = cnt[w];

    const unsigned* Hu = (const unsigned*)Hb;
    float2 acc;
    if (F == 128) {
        unsigned u = Hu[w * 64 + lane];
        acc.x = bf16lo(u);
        acc.y = bf16hi(u);
    } else {
        acc.x = bf16lo((unsigned)Hb[w * 64 + lane]) * 0.0f +
                __uint_as_float(((unsigned)Hb[w * 64 + lane]) << 16);
        acc.y = 0.0f;
    }

    for (int base = 0; base < d; base += 64) {
        int rem = d - base;
        if (rem > 64) rem = 64;
        int cl = (lane < rem) ? csr[s + base + lane] : 0;  // coalesced chunk load

        int e = 0;
        for (; e + 8 <= rem; e += 8) {
            int c0 = __shfl(cl, e + 0);
            int c1 = __shfl(cl, e + 1);
            int c2 = __shfl(cl, e + 2);
            int c3 = __shfl(cl, e + 3);
            int c4 = __shfl(cl, e + 4);
            int c5 = __shfl(cl, e + 5);
            int c6 = __shfl(cl, e + 6);
            int c7 = __shfl(cl, e + 7);
            if (F == 128) {
                unsigned u0 = Hu[c0 * 64 + lane];
                unsigned u1 = Hu[c1 * 64 + lane];
                unsigned u2 = Hu[c2 * 64 + lane];
                unsigned u3 = Hu[c3 * 64 + lane];
                unsigned u4 = Hu[c4 * 64 + lane];
                unsigned u5 = Hu[c5 * 64 + lane];
                unsigned u6 = Hu[c6 * 64 + lane];
                unsigned u7 = Hu[c7 * 64 + lane];
                acc.x += ((bf16lo(u0) + bf16lo(u1)) + (bf16lo(u2) + bf16lo(u3))) +
                         ((bf16lo(u4) + bf16lo(u5)) + (bf16lo(u6) + bf16lo(u7)));
                acc.y += ((bf16hi(u0) + bf16hi(u1)) + (bf16hi(u2) + bf16hi(u3))) +
                         ((bf16hi(u4) + bf16hi(u5)) + (bf16hi(u6) + bf16hi(u7)));
            } else {
                float h0 = __uint_as_float(((unsigned)Hb[c0 * 64 + lane]) << 16);
                float h1 = __uint_as_float(((unsigned)Hb[c1 * 64 + lane]) << 16);
                float h2 = __uint_as_float(((unsigned)Hb[c2 * 64 + lane]) << 16);
                float h3 = __uint_as_float(((unsigned)Hb[c3 * 64 + lane]) << 16);
                float h4 = __uint_as_float(((unsigned)Hb[c4 * 64 + lane]) << 16);
                float h5 = __uint_as_float(((unsigned)Hb[c5 * 64 + lane]) << 16);
                float h6 = __uint_as_float(((unsigned)Hb[c6 * 64 + lane]) << 16);
                float h7 = __uint_as_float(((unsigned)Hb[c7 * 64 + lane]) << 16);
                acc.x += ((h0 + h1) + (h2 + h3)) + ((h4 + h5) + (h6 + h7));
            }
        }
        for (; e < rem; ++e) {
            int c0 = __shfl(cl, e);
            if (F == 128) {
                unsigned u0 = Hu[c0 * 64 + lane];
                acc.x += bf16lo(u0);
                acc.y += bf16hi(u0);
            } else {
                acc.x += __uint_as_float(((unsigned)Hb[c0 * 64 + lane]) << 16);
            }
        }
    }

    acc.x *= di;
    acc.y *= di;
    if (RELU) { acc.x = fmaxf(acc.x, 0.f); acc.y = fmaxf(acc.y, 0.f); }
    if (F == 128) {
        ((float2*)out)[w * 64 + lane] = acc;  // cols 2*lane, 2*lane+1
    } else {
        out[w * 64 + lane] = acc.x;
    }
}

// ---------------------------------------------------------------------------
extern "C" void kernel_launch(void* const* d_in, const int* in_sizes, int n_in,
                              void* d_out, int out_size, void* d_ws, size_t ws_size,
                              hipStream_t stream) {
    const float* x  = (const float*)d_in[0];
    const void*  ei = d_in[1];
    const float* W1 = (const float*)d_in[3];
    const float* b1 = (const float*)d_in[4];
    const float* W2 = (const float*)d_in[5];
    const float* b2 = (const float*)d_in[6];
    float* out = (float*)d_out;

    const int IN = 128, HID = 128, OUT = 64;
    const int N = in_sizes[0] / IN;
    const int E = in_sizes[1] / 2;

    char* ws = (char*)d_ws;
    size_t off = 0;
    auto alloc = [&](size_t bytes) -> void* {
        void* p = (void*)(ws + off);
        off += (bytes + 255) & ~(size_t)255;
        return p;
    };
    int*   cnt    = (int*)alloc((size_t)N * 4);
    int*   cursor = (int*)alloc((size_t)N * 4);
    int*   offs   = (int*)alloc((size_t)N * 4);
    int*   bsums  = (int*)alloc(512);
    int*   flag   = (int*)alloc(256);
    float* dis    = (float*)alloc((size_t)N * 4);
    int*   csr    = (int*)alloc((size_t)E * 4);
    unsigned short* H1b = (unsigned short*)alloc((size_t)N * HID * 2);  // bf16
    float*          R1  = (float*)alloc((size_t)N * HID * 4);           // fp32
    unsigned short* H2b = H1b;  // reuse: H1b dead after agg1 (N*OUT*2 <= N*HID*2)

    hipMemsetAsync(cnt, 0, (size_t)N * 4, stream);
    hipMemsetAsync(cursor, 0, (size_t)N * 4, stream);

    detect64_kernel<<<1, 64, 0, stream>>>((const int*)ei, flag);

    int egrid = (E + TPB - 1) / TPB;
    count_deg_kernel<<<egrid, TPB, 0, stream>>>(ei, E, cnt, flag, N);

    int nb = (N + 1023) / 1024;
    scan1_kernel<<<nb, TPB, 0, stream>>>(cnt, offs, bsums, dis, N);
    scan2_kernel<<<1, 128, 0, stream>>>(bsums, nb);
    scan3_kernel<<<nb, TPB, 0, stream>>>(offs, bsums, N);

    fill_csr_kernel<<<egrid, TPB, 0, stream>>>(ei, E, offs, cursor, csr, flag, N);

    int ngrid = (N + 127) / 128;

    // layer 1: H1b = bf16(dis .* (X@W1^T + b1)) ; R1 = relu(dis .* (self + gather))
    gemm_tiled_kernel<128><<<ngrid, 256, 0, stream>>>(x, W1, b1, dis, H1b, N);
    agg_kernel<128, true><<<(N + 3) / 4, TPB, 0, stream>>>(H1b, csr, offs, cnt, dis, R1, N);

    // layer 2: H2b = bf16(dis .* (R1@W2^T + b2)) ; out = dis .* (self + gather)
    gemm_tiled_kernel<64><<<ngrid, 256, 0, stream>>>(R1, W2, b2, dis, H2b, N);
    agg_kernel<64, false><<<(N + 3) / 4, TPB, 0, stream>>>(H2b, csr, offs, cnt, dis, out, N);
}

// Round 5
// 424.668 us; speedup vs baseline: 1.8239x; 1.1326x over previous
//
#include <hip/hip_runtime.h>
#include <hip/hip_bf16.h>
#include <stdint.h>

// GCN 2-layer forward: out = A_hat @ relu(A_hat @ (X W1^T + b1)) W2^T + b2
// A_hat = D^-1/2 (A + I) D^-1/2, pull-based CSR aggregation (no fp32 atomics).
// GEMM epilogue pre-scales rows by dis[n] and stores H' in BF16 (halves gather
// bytes); aggregation gathers bf16, accumulates fp32.
// CSR build: count pass also emits per-edge rank (atomic return); fill pass is
// atomic-free and XCD-row-partitioned so scattered csr writes stay in one L2.

#define TPB 256

__device__ __forceinline__ float bf16lo(unsigned u) { return __uint_as_float(u << 16); }
__device__ __forceinline__ float bf16hi(unsigned u) { return __uint_as_float(u & 0xffff0000u); }
__device__ __forceinline__ unsigned short f2bf(float f) {
    unsigned u = __float_as_uint(f);
    return (unsigned short)((u + 0x7fff + ((u >> 16) & 1)) >> 16);  // RNE
}

// ---------------------------------------------------------------------------
// dtype probe: edge_index may arrive as int32 or int64. If int64 (values < 2^31,
// non-negative), every odd 32-bit word of the first 64 entries is 0.
__global__ void detect64_kernel(const int* __restrict__ ei32, int* __restrict__ flag) {
    if (threadIdx.x == 0 && blockIdx.x == 0) {
        int is64 = 1;
        for (int t = 0; t < 64; ++t) {
            if (ei32[2 * t + 1] != 0) { is64 = 0; break; }
        }
        *flag = is64;
    }
}

__device__ __forceinline__ int load_edge(const void* ei, int is64, int pos) {
    return is64 ? (int)((const long long*)ei)[pos] : ((const int*)ei)[pos];
}

// ---------------------------------------------------------------------------
// count + rank: rank[e] = this edge's arrival index among its row's edges.
__global__ __launch_bounds__(TPB) void count_rank_kernel(const void* __restrict__ ei, int E,
                                                         int* __restrict__ cnt,
                                                         int* __restrict__ rank,
                                                         const int* __restrict__ flag, int N) {
    int e = blockIdx.x * TPB + threadIdx.x;
    if (e >= E) return;
    int is64 = *flag;
    int r = load_edge(ei, is64, e);
    int rk = 0;
    if ((unsigned)r < (unsigned)N) rk = atomicAdd(&cnt[r], 1);
    rank[e] = rk;
}

// ---------------------------------------------------------------------------
// scan part 1: per-1024-element tile local exclusive scan + tile totals; also dis[i]
__global__ __launch_bounds__(TPB) void scan1_kernel(const int* __restrict__ cnt,
                                                    int* __restrict__ offs,
                                                    int* __restrict__ bsums,
                                                    float* __restrict__ dis, int N) {
    __shared__ int sm[TPB];
    int tid = threadIdx.x;
    int base = blockIdx.x * 1024 + tid * 4;
    int4 v = make_int4(0, 0, 0, 0);
    if (base + 3 < N) {
        v = *(const int4*)(cnt + base);
    } else {
        if (base + 0 < N) v.x = cnt[base + 0];
        if (base + 1 < N) v.y = cnt[base + 1];
        if (base + 2 < N) v.z = cnt[base + 2];
        if (base + 3 < N) v.w = cnt[base + 3];
    }
    int tsum = v.x + v.y + v.z + v.w;
    sm[tid] = tsum;
    __syncthreads();
    for (int o = 1; o < TPB; o <<= 1) {
        int x = (tid >= o) ? sm[tid - o] : 0;
        __syncthreads();
        sm[tid] += x;
        __syncthreads();
    }
    int excl = sm[tid] - tsum;
    int4 o4;
    o4.x = excl;
    o4.y = o4.x + v.x;
    o4.z = o4.y + v.y;
    o4.w = o4.z + v.z;
    if (base + 3 < N) {
        *(int4*)(offs + base) = o4;
    } else {
        if (base + 0 < N) offs[base + 0] = o4.x;
        if (base + 1 < N) offs[base + 1] = o4.y;
        if (base + 2 < N) offs[base + 2] = o4.z;
        if (base + 3 < N) offs[base + 3] = o4.w;
    }
    if (tid == TPB - 1) bsums[blockIdx.x] = sm[TPB - 1];
    // dis = (deg+self)^{-1/2}
    int vv[4] = {v.x, v.y, v.z, v.w};
#pragma unroll
    for (int t = 0; t < 4; ++t) {
        int i = base + t;
        if (i < N) dis[i] = rsqrtf((float)vv[t] + 1.0f);
    }
}

// scan part 2: exclusive scan over tile sums (nb <= 128)
__global__ void scan2_kernel(int* __restrict__ bsums, int nb) {
    __shared__ int sm[128];
    int tid = threadIdx.x;
    int v = (tid < nb) ? bsums[tid] : 0;
    sm[tid] = v;
    __syncthreads();
    for (int o = 1; o < 128; o <<= 1) {
        int x = (tid >= o) ? sm[tid - o] : 0;
        __syncthreads();
        sm[tid] += x;
        __syncthreads();
    }
    if (tid < nb) bsums[tid] = sm[tid] - v;  // exclusive
}

// scan part 3: add tile offsets
__global__ __launch_bounds__(TPB) void scan3_kernel(int* __restrict__ offs,
                                                    const int* __restrict__ bsums, int N) {
    int add = bsums[blockIdx.x];
    int base = blockIdx.x * 1024 + threadIdx.x * 4;
    if (base + 3 < N) {
        int4 v = *(int4*)(offs + base);
        v.x += add; v.y += add; v.z += add; v.w += add;
        *(int4*)(offs + base) = v;
    } else {
#pragma unroll
        for (int t = 0; t < 4; ++t)
            if (base + t < N) offs[base + t] += add;
    }
}

// ---------------------------------------------------------------------------
// Atomic-free CSR fill, row-partitioned into 8 groups (g = blockIdx & 7 lands
// each group on one XCD under round-robin dispatch). Each group scans all
// edges (coalesced, L3-amortized) and writes only rows in its 1/8 range, so
// the scattered csr/offs lines stay resident in that XCD's L2.
#define FILL_CHUNKS 128
__global__ __launch_bounds__(TPB) void fill_csr_part_kernel(const void* __restrict__ ei, int E,
                                                            const int* __restrict__ offs,
                                                            const int* __restrict__ rank,
                                                            int* __restrict__ csr,
                                                            const int* __restrict__ flag, int N) {
    int g = blockIdx.x & 7;
    int chunk = blockIdx.x >> 3;
    int is64 = *flag;
    int lo = (int)(((long long)N * g) >> 3);
    int hi = (int)(((long long)N * (g + 1)) >> 3);
    for (int e = chunk * TPB + threadIdx.x; e < E; e += FILL_CHUNKS * TPB) {
        int r = load_edge(ei, is64, e);
        if (r >= lo && r < hi) {
            int c = load_edge(ei, is64, E + e);
            if ((unsigned)c < (unsigned)N) csr[offs[r] + rank[e]] = c;
        }
    }
}

// ---------------------------------------------------------------------------
// Tiled fp32 GEMM: H[r, :] = dis[r] * (X[r,:] @ W^T + b),  K = 128, BN == OUTF.
// BM=128 nodes/block, BK=32. Both operands staged (transposed) in LDS; X read
// from global exactly once. 256 threads as 16x16; micro-tile 8 rows x (BN/16)
// cols per thread. Output stored as BF16 (row-major, BN cols).
template <int BN>
__global__ __launch_bounds__(256, 4) void gemm_tiled_kernel(const float* __restrict__ X,
                                                            const float* __restrict__ W,
                                                            const float* __restrict__ bias,
                                                            const float* __restrict__ dis,
                                                            unsigned short* __restrict__ Hb,
                                                            int N) {
    constexpr int BM = 128, BK = 32, K = 128;
    constexpr int BMp = BM + 4;          // padded LDS row stride
    constexpr int BNp = BN + 4;
    constexpr int CN = BN / 16;          // cols per thread: 8 (BN=128) or 4 (BN=64)
    __shared__ float Xs[BK * BMp];
    __shared__ float Ws[BK * BNp];

    const int tid = threadIdx.x;
    const int tx = tid & 15;             // col group
    const int ty = tid >> 4;             // row group
    const int r0 = blockIdx.x * BM;
    const int lrow = tid >> 3;           // 0..31 (staging row)
    const int kq = tid & 7;              // 0..7  (staging k-quad)

    float acc[8][CN];
#pragma unroll
    for (int r = 0; r < 8; ++r)
#pragma unroll
        for (int c = 0; c < CN; ++c) acc[r][c] = 0.0f;

    const float4* Xv = (const float4*)X;
    const float4* Wv = (const float4*)W;

    for (int k0 = 0; k0 < K; k0 += BK) {
        // ---- stage X tile (BM x BK), transposed to Xs[k][m]
#pragma unroll
        for (int p = 0; p < BM / 32; ++p) {
            int row = lrow + p * 32;
            int rg = r0 + row;
            if (rg >= N) rg = N - 1;     // clamp (stores are guarded)
            float4 v = Xv[(size_t)rg * (K / 4) + (k0 >> 2) + kq];
            Xs[(4 * kq + 0) * BMp + row] = v.x;
            Xs[(4 * kq + 1) * BMp + row] = v.y;
            Xs[(4 * kq + 2) * BMp + row] = v.z;
            Xs[(4 * kq + 3) * BMp + row] = v.w;
        }
        // ---- stage W tile (BN x BK), transposed to Ws[k][n]
#pragma unroll
        for (int p = 0; p < BN / 32; ++p) {
            int j = lrow + p * 32;
            float4 v = Wv[(size_t)j * (K / 4) + (k0 >> 2) + kq];
            Ws[(4 * kq + 0) * BNp + j] = v.x;
            Ws[(4 * kq + 1) * BNp + j] = v.y;
            Ws[(4 * kq + 2) * BNp + j] = v.z;
            Ws[(4 * kq + 3) * BNp + j] = v.w;
        }
        __syncthreads();

#pragma unroll 4
        for (int k = 0; k < BK; ++k) {
            float4 xa = *(const float4*)&Xs[k * BMp + 8 * ty];
            float4 xb = *(const float4*)&Xs[k * BMp + 8 * ty + 4];
            float4 wa = *(const float4*)&Ws[k * BNp + 4 * tx];
            float xr[8] = {xa.x, xa.y, xa.z, xa.w, xb.x, xb.y, xb.z, xb.w};
            float wc[CN];
            wc[0] = wa.x; wc[1] = wa.y; wc[2] = wa.z; wc[3] = wa.w;
            if (BN == 128) {
                float4 wb = *(const float4*)&Ws[k * BNp + 64 + 4 * tx];
                wc[4] = wb.x; wc[5] = wb.y; wc[6] = wb.z; wc[7] = wb.w;
            }
#pragma unroll
            for (int r = 0; r < 8; ++r)
#pragma unroll
                for (int c = 0; c < CN; ++c) acc[r][c] += xr[r] * wc[c];
        }
        __syncthreads();
    }

    // ---- epilogue: (+bias) * dis[row], pack bf16, store ushort4 per 4 cols
    float4 bva = *(const float4*)&bias[4 * tx];
    float4 bvb = make_float4(0.f, 0.f, 0.f, 0.f);
    if (BN == 128) bvb = *(const float4*)&bias[64 + 4 * tx];
#pragma unroll
    for (int r = 0; r < 8; ++r) {
        int row = r0 + 8 * ty + r;
        if (row < N) {
            float dn = dis[row];
            ushort4 oa;
            oa.x = f2bf((acc[r][0] + bva.x) * dn);
            oa.y = f2bf((acc[r][1] + bva.y) * dn);
            oa.z = f2bf((acc[r][2] + bva.z) * dn);
            oa.w = f2bf((acc[r][3] + bva.w) * dn);
            *(ushort4*)&Hb[(size_t)row * BN + 4 * tx] = oa;
            if (BN == 128) {
                ushort4 ob;
                ob.x = f2bf((acc[r][4] + bvb.x) * dn);
                ob.y = f2bf((acc[r][5] + bvb.y) * dn);
                ob.z = f2bf((acc[r][6] + bvb.z) * dn);
                ob.w = f2bf((acc[r][7] + bvb.w) * dn);
                *(ushort4*)&Hb[(size_t)row * BN + 64 + 4 * tx] = ob;
            }
        }
    }
}

// ---------------------------------------------------------------------------
// Pull aggregation over pre-scaled bf16 H' (H'[n] = dis[n]*(XW+b)[n]):
//   out[i] = dis[i] * (H'[i] + sum_e H'[col_e]),  optional relu.  fp32 out.
// One wave per node. Edge indices fetched coalesced 64-at-a-time, broadcast
// via shfl; in-loop global op is the bf16 H row gather, 8-way unrolled.
template <int F, bool RELU>
__global__ __launch_bounds__(TPB) void agg_kernel(const unsigned short* __restrict__ Hb,
                                                  const int* __restrict__ csr,
                                                  const int* __restrict__ offs,
                                                  const int* __restrict__ cnt,
                                                  const float* __restrict__ dis,
                                                  float* __restrict__ out, int N) {
    int w = (blockIdx.x * TPB + threadIdx.x) >> 6;
    if (w >= N) return;  // wave-uniform: whole wave exits together
    int lane = threadIdx.x & 63;
    float di = dis[w];
    int s = offs[w];
    int d = cnt[w];

    const unsigned* Hu = (const unsigned*)Hb;
    float2 acc;
    if (F == 128) {
        unsigned u = Hu[w * 64 + lane];
        acc.x = bf16lo(u);
        acc.y = bf16hi(u);
    } else {
        acc.x = __uint_as_float(((unsigned)Hb[w * 64 + lane]) << 16);
        acc.y = 0.0f;
    }

    for (int base = 0; base < d; base += 64) {
        int rem = d - base;
        if (rem > 64) rem = 64;
        int cl = (lane < rem) ? csr[s + base + lane] : 0;  // coalesced chunk load

        int e = 0;
        for (; e + 8 <= rem; e += 8) {
            int c0 = __shfl(cl, e + 0);
            int c1 = __shfl(cl, e + 1);
            int c2 = __shfl(cl, e + 2);
            int c3 = __shfl(cl, e + 3);
            int c4 = __shfl(cl, e + 4);
            int c5 = __shfl(cl, e + 5);
            int c6 = __shfl(cl, e + 6);
            int c7 = __shfl(cl, e + 7);
            if (F == 128) {
                unsigned u0 = Hu[c0 * 64 + lane];
                unsigned u1 = Hu[c1 * 64 + lane];
                unsigned u2 = Hu[c2 * 64 + lane];
                unsigned u3 = Hu[c3 * 64 + lane];
                unsigned u4 = Hu[c4 * 64 + lane];
                unsigned u5 = Hu[c5 * 64 + lane];
                unsigned u6 = Hu[c6 * 64 + lane];
                unsigned u7 = Hu[c7 * 64 + lane];
                acc.x += ((bf16lo(u0) + bf16lo(u1)) + (bf16lo(u2) + bf16lo(u3))) +
                         ((bf16lo(u4) + bf16lo(u5)) + (bf16lo(u6) + bf16lo(u7)));
                acc.y += ((bf16hi(u0) + bf16hi(u1)) + (bf16hi(u2) + bf16hi(u3))) +
                         ((bf16hi(u4) + bf16hi(u5)) + (bf16hi(u6) + bf16hi(u7)));
            } else {
                float h0 = __uint_as_float(((unsigned)Hb[c0 * 64 + lane]) << 16);
                float h1 = __uint_as_float(((unsigned)Hb[c1 * 64 + lane]) << 16);
                float h2 = __uint_as_float(((unsigned)Hb[c2 * 64 + lane]) << 16);
                float h3 = __uint_as_float(((unsigned)Hb[c3 * 64 + lane]) << 16);
                float h4 = __uint_as_float(((unsigned)Hb[c4 * 64 + lane]) << 16);
                float h5 = __uint_as_float(((unsigned)Hb[c5 * 64 + lane]) << 16);
                float h6 = __uint_as_float(((unsigned)Hb[c6 * 64 + lane]) << 16);
                float h7 = __uint_as_float(((unsigned)Hb[c7 * 64 + lane]) << 16);
                acc.x += ((h0 + h1) + (h2 + h3)) + ((h4 + h5) + (h6 + h7));
            }
        }
        for (; e < rem; ++e) {
            int c0 = __shfl(cl, e);
            if (F == 128) {
                unsigned u0 = Hu[c0 * 64 + lane];
                acc.x += bf16lo(u0);
                acc.y += bf16hi(u0);
            } else {
                acc.x += __uint_as_float(((unsigned)Hb[c0 * 64 + lane]) << 16);
            }
        }
    }

    acc.x *= di;
    acc.y *= di;
    if (RELU) { acc.x = fmaxf(acc.x, 0.f); acc.y = fmaxf(acc.y, 0.f); }
    if (F == 128) {
        ((float2*)out)[w * 64 + lane] = acc;  // cols 2*lane, 2*lane+1
    } else {
        out[w * 64 + lane] = acc.x;
    }
}

// ---------------------------------------------------------------------------
extern "C" void kernel_launch(void* const* d_in, const int* in_sizes, int n_in,
                              void* d_out, int out_size, void* d_ws, size_t ws_size,
                              hipStream_t stream) {
    const float* x  = (const float*)d_in[0];
    const void*  ei = d_in[1];
    const float* W1 = (const float*)d_in[3];
    const float* b1 = (const float*)d_in[4];
    const float* W2 = (const float*)d_in[5];
    const float* b2 = (const float*)d_in[6];
    float* out = (float*)d_out;

    const int IN = 128, HID = 128, OUT = 64;
    const int N = in_sizes[0] / IN;
    const int E = in_sizes[1] / 2;

    char* ws = (char*)d_ws;
    size_t off = 0;
    auto alloc = [&](size_t bytes) -> void* {
        void* p = (void*)(ws + off);
        off += (bytes + 255) & ~(size_t)255;
        return p;
    };
    int*   cnt    = (int*)alloc((size_t)N * 4);
    int*   offs   = (int*)alloc((size_t)N * 4);
    int*   bsums  = (int*)alloc(512);
    int*   flag   = (int*)alloc(256);
    float* dis    = (float*)alloc((size_t)N * 4);
    int*   rank   = (int*)alloc((size_t)E * 4);
    int*   csr    = (int*)alloc((size_t)E * 4);
    unsigned short* H1b = (unsigned short*)alloc((size_t)N * HID * 2);  // bf16
    float*          R1  = (float*)alloc((size_t)N * HID * 4);           // fp32
    unsigned short* H2b = H1b;  // reuse: H1b dead after agg1 (N*OUT*2 <= N*HID*2)

    hipMemsetAsync(cnt, 0, (size_t)N * 4, stream);

    detect64_kernel<<<1, 64, 0, stream>>>((const int*)ei, flag);

    int egrid = (E + TPB - 1) / TPB;
    count_rank_kernel<<<egrid, TPB, 0, stream>>>(ei, E, cnt, rank, flag, N);

    int nb = (N + 1023) / 1024;
    scan1_kernel<<<nb, TPB, 0, stream>>>(cnt, offs, bsums, dis, N);
    scan2_kernel<<<1, 128, 0, stream>>>(bsums, nb);
    scan3_kernel<<<nb, TPB, 0, stream>>>(offs, bsums, N);

    fill_csr_part_kernel<<<8 * FILL_CHUNKS, TPB, 0, stream>>>(ei, E, offs, rank, csr, flag, N);

    int ngrid = (N + 127) / 128;

    // layer 1: H1b = bf16(dis .* (X@W1^T + b1)) ; R1 = relu(dis .* (self + gather))
    gemm_tiled_kernel<128><<<ngrid, 256, 0, stream>>>(x, W1, b1, dis, H1b, N);
    agg_kernel<128, true><<<(N + 3) / 4, TPB, 0, stream>>>(H1b, csr, offs, cnt, dis, R1, N);

    // layer 2: H2b = bf16(dis .* (R1@W2^T + b2)) ; out = dis .* (self + gather)
    gemm_tiled_kernel<64><<<ngrid, 256, 0, stream>>>(R1, W2, b2, dis, H2b, N);
    agg_kernel<64, false><<<(N + 3) / 4, TPB, 0, stream>>>(H2b, csr, offs, cnt, dis, out, N);
}